// Round 6
// baseline (262.776 us; speedup 1.0000x reference)
//
#include <hip/hip_runtime.h>
#include <hip/hip_bf16.h>
#include <stdint.h>

typedef __attribute__((ext_vector_type(4))) float f32x4;
typedef __attribute__((ext_vector_type(8))) short bf16x8;
typedef __attribute__((ext_vector_type(4))) float float4v;

static constexpr int KD    = 1024;   // hidden dim
static constexpr int ND    = 2048;   // expert out dim (gate+up)
static constexpr int NE    = 8;      // experts
static constexpr int MROWS = 16384;  // hidden rows
static constexpr int RFLAT = 32768;  // M * topk
static constexpr int OUTN  = 1024;   // output cols (ND/2)

// ws ints: cnt[8]@0, cursor[8]@8, offs[9]@16, mode@31, tileoff[9]@40
static constexpr size_t WS_ROWLIST = 1024;
static constexpr size_t WS_HB      = 262144;
static constexpr size_t WS_WT      = 262144 + (size_t)33554432;

__device__ __forceinline__ unsigned short f2bf(float f) {
  uint32_t u = __float_as_uint(f);
  uint32_t r = (u + 0x7FFFu + ((u >> 16) & 1u)) >> 16;
  return (unsigned short)r;
}

__device__ __forceinline__ void gload16(const void* g, void* l) {
  __builtin_amdgcn_global_load_lds(
      (__attribute__((address_space(1))) void*)(void*)g,
      (__attribute__((address_space(3))) void*)l, 16, 0, 0);
}

// Detect int32-converted vs raw-int64 ids (odd 32-bit slots all zero => int64).
__global__ void k_detect(const int* __restrict__ ids32, int* __restrict__ wsi) {
  int t = blockIdx.x * 256 + threadIdx.x;
  int i = 2 * t + 1;
  if (i < RFLAT && ids32[i] != 0) atomicOr(&wsi[31], 1);
}

__device__ __forceinline__ int read_id(const int* ids32, int t, int mode) {
  return (mode ? ids32[t] : ids32[2 * t]) & 7;
}

// LDS-histogram count.
__global__ void k_count(const int* __restrict__ ids, int* __restrict__ wsi) {
  __shared__ int h[8];
  const int tid = threadIdx.x;
  if (tid < 8) h[tid] = 0;
  __syncthreads();
  const int mode = wsi[31];
  const int base = blockIdx.x * 512 + tid;
  atomicAdd(&h[read_id(ids, base, mode)], 1);
  atomicAdd(&h[read_id(ids, base + 256, mode)], 1);
  __syncthreads();
  if (tid < 8 && h[tid]) atomicAdd(&wsi[tid], h[tid]);
}

__global__ void k_scan(int* wsi) {
  if (threadIdx.x == 0) {
    int o = 0, to = 0;
    for (int e = 0; e < NE; ++e) {
      int c = wsi[e];
      wsi[16 + e] = o;   // offs
      wsi[8 + e]  = o;   // cursor
      wsi[40 + e] = to;  // tile offset (256-row tiles)
      o += c;
      to += (c + 255) / 256;
    }
    wsi[16 + NE] = o;
    wsi[40 + NE] = to;
  }
}

// LDS-histogram scatter: per-block base + local rank.
__global__ void k_scatter(const int* __restrict__ ids, int* __restrict__ wsi,
                          int* __restrict__ rowlist) {
  __shared__ int h[8], base[8], c2[8];
  const int tid = threadIdx.x;
  if (tid < 8) { h[tid] = 0; c2[tid] = 0; }
  __syncthreads();
  const int mode = wsi[31];
  const int t = blockIdx.x * 256 + tid;
  const int e = read_id(ids, t, mode);
  atomicAdd(&h[e], 1);
  __syncthreads();
  if (tid < 8 && h[tid]) base[tid] = atomicAdd(&wsi[8 + tid], h[tid]);
  __syncthreads();
  const int r = atomicAdd(&c2[e], 1);
  rowlist[base[e] + r] = t;
}

__global__ void k_cvtH(const float* __restrict__ H, unsigned short* __restrict__ Hb) {
  const int n4 = (MROWS * KD) / 4;
  const int stride = gridDim.x * blockDim.x;
  for (int i = blockIdx.x * blockDim.x + threadIdx.x; i < n4; i += stride) {
    float4v v = ((const float4v*)H)[i];
    ushort4 o;
    o.x = f2bf(v.x); o.y = f2bf(v.y); o.z = f2bf(v.z); o.w = f2bf(v.w);
    ((ushort4*)Hb)[i] = o;
  }
}

// Transpose + convert: W[e][k][n] fp32 -> Wt[e][n][k] bf16 (64x64 tiles).
__global__ void k_cvtW(const float* __restrict__ W, unsigned short* __restrict__ Wt) {
  __shared__ float tile[64][65];
  const int e  = blockIdx.z;
  const int n0 = blockIdx.x * 64;
  const int k0 = blockIdx.y * 64;
  const int tx = threadIdx.x, ty = threadIdx.y;
  const float* Wp = W + (size_t)e * KD * ND;
  #pragma unroll
  for (int i = ty; i < 64; i += 8)
    tile[i][tx] = Wp[(size_t)(k0 + i) * ND + n0 + tx];
  __syncthreads();
  unsigned short* Wo = Wt + (size_t)e * ND * KD;
  #pragma unroll
  for (int i = ty; i < 64; i += 8)
    Wo[(size_t)(n0 + i) * KD + k0 + tx] = f2bf(tile[tx][i]);
}

// Grouped GEMM: depth-3 counted-vmcnt pipeline (T3+T4).
// 256 rows x 256 wcols, BK=32, 32 K-steps, 512 threads = 8 waves (2Mx4N),
// wave tile 128x64, acc[8][4]. LDS: 4 buffers x 32KB (A 16K @0, B 16K @16K),
// rows of 64B, chunk slot c_l holds global chunk c_l ^ ((row>>1)&3) ->
// 2-way-free ds_read_b128; source pre-swizzled, dest linear (rule 21).
// Per step: STAGE(k+3) -> COMPUTE(k) -> s_waitcnt vmcnt(8) + s_barrier.
// vmcnt(8) retires tile k+1 (4 loads/thread), leaves tiles k+2,k+3 in flight:
// loads issued ~3 compute phases before use -> latency hidden, never vmcnt(0).
__global__ __launch_bounds__(512, 2) void k_gemm(
    const unsigned short* __restrict__ Hb, const unsigned short* __restrict__ Wt,
    const int* __restrict__ wsi, const int* __restrict__ rowlist,
    float* __restrict__ Out) {
  const int bid = blockIdx.x;
  const int xcd = bid & 7;
  const int j   = bid >> 3;
  const int colblk = j & 7;        // col-blocks fastest within an XCD
  const int rt  = xcd + (j >> 3) * 8;
  if (rt >= wsi[48]) return;
  int e = 0;
  #pragma unroll
  for (int q = 1; q < 8; ++q)
    if (rt >= wsi[40 + q]) e = q;
  const int cnt = wsi[e];
  const int tile_base = (rt - wsi[40 + e]) * 256;
  const int tile_cnt = min(256, cnt - tile_base);
  const int off = wsi[16 + e] + tile_base;
  const int c0 = colblk * 128;     // out-col base

  __shared__ char lds[131072];
  __shared__ int s_rows[256];

  const int t = threadIdx.x;
  if (t < 256) s_rows[t] = rowlist[off + min(t, tile_cnt - 1)];
  __syncthreads();

  // Staging: thread t covers LDS row (t>>2), chunk slot (t&3); 4 lanes cover
  // one row's contiguous 64B (coalesced). Source chunk g = (t&3) ^ ((t>>3)&3)
  // pre-applies the read-side swizzle sigma(row) = (row>>1)&3.
  const int srow = t >> 2;
  const int g16 = ((t & 3) ^ ((t >> 3) & 3)) * 16;
  const char* srcA[2];
  const char* srcB[2];
  #pragma unroll
  for (int u = 0; u < 2; ++u) {
    const int row_a = u * 128 + srow;
    srcA[u] = (const char*)Hb + (size_t)(s_rows[row_a] >> 1) * (KD * 2) + g16;
    const int jb = u * 128 + srow;           // B LDS col index
    const int wn_s = jb >> 6, r64 = jb & 63;
    const int h_s = r64 >> 4, l_s = r64 & 15;
    const int wcol = (h_s < 2) ? (c0 + wn_s * 32 + h_s * 16 + l_s)
                               : (OUTN + c0 + wn_s * 32 + (h_s - 2) * 16 + l_s);
    srcB[u] = (const char*)Wt + ((size_t)e * ND + wcol) * (KD * 2) + g16;
  }

  const int lane = t & 63, wid = t >> 6;
  const int wm = wid >> 2, wn = wid & 3;
  const int kc = lane >> 4, l15 = lane & 15;

  f32x4 acc[8][4];
  #pragma unroll
  for (int m = 0; m < 8; ++m)
    #pragma unroll
    for (int h = 0; h < 4; ++h)
      acc[m][h] = (f32x4){0.f, 0.f, 0.f, 0.f};

  // ds_read offsets within a buffer: A row r @ r*64, B col j @ 16384 + j*64;
  // chunk slot = kc ^ ((row>>1)&3).
  int aoff[8], boff[4];
  #pragma unroll
  for (int m = 0; m < 8; ++m) {
    const int r = wm * 128 + m * 16 + l15;
    aoff[m] = r * 64 + (kc ^ ((r >> 1) & 3)) * 16;
  }
  #pragma unroll
  for (int h = 0; h < 4; ++h) {
    const int jb = wn * 64 + h * 16 + l15;
    boff[h] = 16384 + jb * 64 + (kc ^ ((jb >> 1) & 3)) * 16;
  }

  auto STAGE = [&](int kt, int b) {
    const int go = kt * 64;
    char* base = lds + b * 32768 + t * 16;
    gload16(srcA[0] + go, base);
    gload16(srcA[1] + go, base + 8192);
    gload16(srcB[0] + go, base + 16384);
    gload16(srcB[1] + go, base + 24576);
  };
  auto COMPUTE = [&](int b) {
    const char* cb = lds + b * 32768;
    bf16x8 af[8], bfv[4];
    #pragma unroll
    for (int m = 0; m < 8; ++m) af[m] = *(const bf16x8*)(cb + aoff[m]);
    #pragma unroll
    for (int h = 0; h < 4; ++h) bfv[h] = *(const bf16x8*)(cb + boff[h]);
    #pragma unroll
    for (int m = 0; m < 8; ++m)
      #pragma unroll
      for (int h = 0; h < 4; ++h)
        acc[m][h] = __builtin_amdgcn_mfma_f32_16x16x32_bf16(af[m], bfv[h], acc[m][h], 0, 0, 0);
  };

  // Prologue: fill 3 buffers (12 loads/thread); wait for tile 0 only.
  STAGE(0, 0); STAGE(1, 1); STAGE(2, 2);
  asm volatile("s_waitcnt vmcnt(8)\ns_barrier" ::: "memory");

  // Main: 29 iterations with constant counted wait.
  for (int k = 0; k < 29; ++k) {
    STAGE(k + 3, (k + 3) & 3);
    COMPUTE(k & 3);
    asm volatile("s_waitcnt vmcnt(8)\ns_barrier" ::: "memory");
  }
  // Tail: tiles 29,30,31 already staged.
  COMPUTE(29 & 3);
  asm volatile("s_waitcnt vmcnt(4)\ns_barrier" ::: "memory");
  COMPUTE(30 & 3);
  asm volatile("s_waitcnt vmcnt(0)\ns_barrier" ::: "memory");
  COMPUTE(31 & 3);

  // Fused epilogue: gate = acc[m][h], up = acc[m][h+2], h in {0,1}.
  #pragma unroll
  for (int m = 0; m < 8; ++m) {
    const int rbase = wm * 128 + m * 16 + kc * 4;
    #pragma unroll
    for (int i = 0; i < 4; ++i) {
      const int rl = rbase + i;
      if (rl < tile_cnt) {
        const size_t orow = (size_t)s_rows[rl] * OUTN;
        #pragma unroll
        for (int h = 0; h < 2; ++h) {
          float gg = acc[m][h][i];
          float uu = acc[m][h + 2][i];
          float s = gg / (1.0f + __expf(-gg)) * uu;
          Out[orow + c0 + wn * 32 + h * 16 + l15] = s;
        }
      }
    }
  }
}

extern "C" void kernel_launch(void* const* d_in, const int* in_sizes, int n_in,
                              void* d_out, int out_size, void* d_ws, size_t ws_size,
                              hipStream_t stream) {
  const float* H  = (const float*)d_in[0];
  const float* W  = (const float*)d_in[1];
  const int* ids  = (const int*)d_in[2];
  float* Out      = (float*)d_out;
  char* ws        = (char*)d_ws;
  int* wsi        = (int*)ws;
  int* rowlist    = (int*)(ws + WS_ROWLIST);
  unsigned short* Hb = (unsigned short*)(ws + WS_HB);
  unsigned short* Wt = (unsigned short*)(ws + WS_WT);

  hipMemsetAsync(ws, 0, 1024, stream);
  k_detect<<<RFLAT / 2 / 256, 256, 0, stream>>>(ids, wsi);
  k_count<<<RFLAT / 512, 256, 0, stream>>>(ids, wsi);
  k_scan<<<1, 64, 0, stream>>>(wsi);
  k_scatter<<<RFLAT / 256, 256, 0, stream>>>(ids, wsi, rowlist);
  k_cvtH<<<2048, 256, 0, stream>>>(H, Hb);
  k_cvtW<<<dim3(ND / 64, KD / 64, NE), dim3(64, 8), 0, stream>>>(W, Wt);
  // rowtiles (256-row) <= 135; 17 slots per XCD x 8 XCDs x 8 colblocks
  k_gemm<<<8 * 17 * 8, 512, 0, stream>>>(Hb, Wt, wsi, rowlist, Out);
}

// Round 7
// 236.010 us; speedup vs baseline: 1.1134x; 1.1134x over previous
//
#include <hip/hip_runtime.h>
#include <hip/hip_bf16.h>
#include <stdint.h>

typedef __attribute__((ext_vector_type(4))) float f32x4;
typedef __attribute__((ext_vector_type(8))) short bf16x8;
typedef __attribute__((ext_vector_type(4))) float float4v;

static constexpr int KD    = 1024;   // hidden dim
static constexpr int ND    = 2048;   // expert out dim (gate+up)
static constexpr int NE    = 8;      // experts
static constexpr int MROWS = 16384;  // hidden rows
static constexpr int RFLAT = 32768;  // M * topk
static constexpr int OUTN  = 1024;   // output cols (ND/2)

// ws ints: cnt[8]@0, cursor[8]@8, offs[9]@16, mode@31, tileoff[9]@40
static constexpr size_t WS_ROWLIST = 1024;
static constexpr size_t WS_HB      = 262144;
static constexpr size_t WS_WT      = 262144 + (size_t)33554432;

__device__ __forceinline__ unsigned short f2bf(float f) {
  uint32_t u = __float_as_uint(f);
  uint32_t r = (u + 0x7FFFu + ((u >> 16) & 1u)) >> 16;
  return (unsigned short)r;
}

__device__ __forceinline__ void gload16(const void* g, void* l) {
  __builtin_amdgcn_global_load_lds(
      (__attribute__((address_space(1))) void*)(void*)g,
      (__attribute__((address_space(3))) void*)l, 16, 0, 0);
}

// Detect int32-converted vs raw-int64 ids (odd 32-bit slots all zero => int64).
__global__ void k_detect(const int* __restrict__ ids32, int* __restrict__ wsi) {
  int t = blockIdx.x * 256 + threadIdx.x;
  int i = 2 * t + 1;
  if (i < RFLAT && ids32[i] != 0) atomicOr(&wsi[31], 1);
}

__device__ __forceinline__ int read_id(const int* ids32, int t, int mode) {
  return (mode ? ids32[t] : ids32[2 * t]) & 7;
}

// LDS-histogram count.
__global__ void k_count(const int* __restrict__ ids, int* __restrict__ wsi) {
  __shared__ int h[8];
  const int tid = threadIdx.x;
  if (tid < 8) h[tid] = 0;
  __syncthreads();
  const int mode = wsi[31];
  const int base = blockIdx.x * 512 + tid;
  atomicAdd(&h[read_id(ids, base, mode)], 1);
  atomicAdd(&h[read_id(ids, base + 256, mode)], 1);
  __syncthreads();
  if (tid < 8 && h[tid]) atomicAdd(&wsi[tid], h[tid]);
}

__global__ void k_scan(int* wsi) {
  if (threadIdx.x == 0) {
    int o = 0, to = 0;
    for (int e = 0; e < NE; ++e) {
      int c = wsi[e];
      wsi[16 + e] = o;   // offs
      wsi[8 + e]  = o;   // cursor
      wsi[40 + e] = to;  // tile offset (256-row tiles)
      o += c;
      to += (c + 255) / 256;
    }
    wsi[16 + NE] = o;
    wsi[40 + NE] = to;
  }
}

// LDS-histogram scatter: per-block base + local rank.
__global__ void k_scatter(const int* __restrict__ ids, int* __restrict__ wsi,
                          int* __restrict__ rowlist) {
  __shared__ int h[8], base[8], c2[8];
  const int tid = threadIdx.x;
  if (tid < 8) { h[tid] = 0; c2[tid] = 0; }
  __syncthreads();
  const int mode = wsi[31];
  const int t = blockIdx.x * 256 + tid;
  const int e = read_id(ids, t, mode);
  atomicAdd(&h[e], 1);
  __syncthreads();
  if (tid < 8 && h[tid]) base[tid] = atomicAdd(&wsi[8 + tid], h[tid]);
  __syncthreads();
  const int r = atomicAdd(&c2[e], 1);
  rowlist[base[e] + r] = t;
}

__global__ void k_cvtH(const float* __restrict__ H, unsigned short* __restrict__ Hb) {
  const int n4 = (MROWS * KD) / 4;
  const int stride = gridDim.x * blockDim.x;
  for (int i = blockIdx.x * blockDim.x + threadIdx.x; i < n4; i += stride) {
    float4v v = ((const float4v*)H)[i];
    ushort4 o;
    o.x = f2bf(v.x); o.y = f2bf(v.y); o.z = f2bf(v.z); o.w = f2bf(v.w);
    ((ushort4*)Hb)[i] = o;
  }
}

// Transpose + convert: W[e][k][n] fp32 -> Wt[e][n][k] bf16 (64x64 tiles).
__global__ void k_cvtW(const float* __restrict__ W, unsigned short* __restrict__ Wt) {
  __shared__ float tile[64][65];
  const int e  = blockIdx.z;
  const int n0 = blockIdx.x * 64;
  const int k0 = blockIdx.y * 64;
  const int tx = threadIdx.x, ty = threadIdx.y;
  const float* Wp = W + (size_t)e * KD * ND;
  #pragma unroll
  for (int i = ty; i < 64; i += 8)
    tile[i][tx] = Wp[(size_t)(k0 + i) * ND + n0 + tx];
  __syncthreads();
  unsigned short* Wo = Wt + (size_t)e * ND * KD;
  #pragma unroll
  for (int i = ty; i < 64; i += 8)
    Wo[(size_t)(n0 + i) * KD + k0 + tx] = f2bf(tile[tx][i]);
}

// Grouped GEMM: m201-style 4-phase/K-tile schedule, counted vmcnt.
// 256 rows x 256 wcols, BK=64, 16 K-tiles, 512 threads = 8 waves (2Mx4N),
// wave tile 128x64, acc[8][4]. LDS: 2 dbuf x 64KB; each buffer split in
// k-sub quarters: Aq (q*16K, 256 rows x 64B) and Bq (32K + q*16K).
// Swizzle: slot s of row r holds global chunk s ^ ((r>>1)&3); staged with
// linear LDS dest + pre-swizzled source (rule 21); 2-way-free ds_read_b128.
// Per phase: {ds_read 4|8 ; stage 1 quarter (2 gloads)} -> [vmcnt(4) @P2,P4]
// -> barrier -> setprio(1) 16 MFMA setprio(0) -> barrier. Each quarter is
// vmcnt-waited 3 phases after issue; never vmcnt(0) in the main loop.
__global__ __launch_bounds__(512, 2) void k_gemm(
    const unsigned short* __restrict__ Hb, const unsigned short* __restrict__ Wt,
    const int* __restrict__ wsi, const int* __restrict__ rowlist,
    float* __restrict__ Out) {
  const int bid = blockIdx.x;
  const int xcd = bid & 7;
  const int j   = bid >> 3;
  const int colblk = j & 7;        // col-blocks fastest within an XCD
  const int rt  = xcd + (j >> 3) * 8;
  if (rt >= wsi[48]) return;
  int e = 0;
  #pragma unroll
  for (int q = 1; q < 8; ++q)
    if (rt >= wsi[40 + q]) e = q;
  const int cnt = wsi[e];
  const int tile_base = (rt - wsi[40 + e]) * 256;
  const int tile_cnt = min(256, cnt - tile_base);
  const int off = wsi[16 + e] + tile_base;
  const int c0 = colblk * 128;     // out-col base

  __shared__ char lds[131072];
  __shared__ int s_rows[256];

  const int t = threadIdx.x;
  if (t < 256) s_rows[t] = rowlist[off + min(t, tile_cnt - 1)];
  __syncthreads();

  // Staging: thread t covers rows/cols (t>>2) and 128+(t>>2), slot t&3.
  // Source chunk = (t&3) ^ ((t>>3)&3) pre-applies read swizzle sigma(r)=(r>>1)&3
  // (identical for r and r+128). Per gload instruction: 16 rows x 64B coalesced.
  const int srow = t >> 2;
  const int coff = ((t & 3) ^ ((t >> 3) & 3)) * 16;
  const char* sA0 = (const char*)Hb + (size_t)(s_rows[srow] >> 1) * (KD * 2) + coff;
  const char* sA1 = (const char*)Hb + (size_t)(s_rows[128 + srow] >> 1) * (KD * 2) + coff;
  auto wcol_of = [&](int jc) {
    const int wn_s = jc >> 6, r64 = jc & 63;
    const int h_s = r64 >> 4, l_s = r64 & 15;
    return (h_s < 2) ? (c0 + wn_s * 32 + h_s * 16 + l_s)
                     : (OUTN + c0 + wn_s * 32 + (h_s - 2) * 16 + l_s);
  };
  const char* sB0 = (const char*)Wt + ((size_t)e * ND + wcol_of(srow)) * (KD * 2) + coff;
  const char* sB1 = (const char*)Wt + ((size_t)e * ND + wcol_of(128 + srow)) * (KD * 2) + coff;

  const int lane = t & 63, wid = t >> 6;
  const int wm = wid >> 2, wn = wid & 3;
  const int kc = lane >> 4, l15 = lane & 15;

  f32x4 acc[8][4];
  #pragma unroll
  for (int m = 0; m < 8; ++m)
    #pragma unroll
    for (int h = 0; h < 4; ++h)
      acc[m][h] = (f32x4){0.f, 0.f, 0.f, 0.f};

  // Fragment ds_read offsets (within one 64KB buffer).
  int aoff[2][8], boff[2][4];
  #pragma unroll
  for (int q = 0; q < 2; ++q) {
    #pragma unroll
    for (int m = 0; m < 8; ++m) {
      const int r = wm * 128 + m * 16 + l15;
      aoff[q][m] = q * 16384 + r * 64 + ((kc ^ ((r >> 1) & 3)) * 16);
    }
    #pragma unroll
    for (int h = 0; h < 4; ++h) {
      const int jb = wn * 64 + h * 16 + l15;
      boff[q][h] = 32768 + q * 16384 + jb * 64 + ((kc ^ ((jb >> 1) & 3)) * 16);
    }
  }

  auto SA = [&](int kt, int q, char* buf) {   // stage A quarter q of tile kt
    const int go = kt * 128 + q * 64;
    gload16(sA0 + go, buf + q * 16384 + t * 16);
    gload16(sA1 + go, buf + q * 16384 + 8192 + t * 16);
  };
  auto SB = [&](int kt, int q, char* buf) {   // stage B quarter q of tile kt
    const int go = kt * 128 + q * 64;
    gload16(sB0 + go, buf + 32768 + q * 16384 + t * 16);
    gload16(sB1 + go, buf + 32768 + q * 16384 + 8192 + t * 16);
  };

  bf16x8 af[4], bfv[4];
  auto LDA = [&](const char* cb, int q, int mlo) {
    #pragma unroll
    for (int m = 0; m < 4; ++m) af[m] = *(const bf16x8*)(cb + aoff[q][mlo + m]);
  };
  auto LDB = [&](const char* cb, int q) {
    #pragma unroll
    for (int h = 0; h < 4; ++h) bfv[h] = *(const bf16x8*)(cb + boff[q][h]);
  };
  auto MM = [&](int mlo) {
    __builtin_amdgcn_s_setprio(1);
    #pragma unroll
    for (int m = 0; m < 4; ++m)
      #pragma unroll
      for (int h = 0; h < 4; ++h)
        acc[mlo + m][h] =
            __builtin_amdgcn_mfma_f32_16x16x32_bf16(af[m], bfv[h], acc[mlo + m][h], 0, 0, 0);
    __builtin_amdgcn_s_setprio(0);
  };
#define GUARD4 asm volatile("s_waitcnt vmcnt(4)" ::: "memory")
#define GUARD0 asm volatile("s_waitcnt vmcnt(0)" ::: "memory")
#define BAR __builtin_amdgcn_s_barrier()

  // Prologue: stage all 4 quarters of tile 0; wait for Aq0,Bq0 only.
  SA(0, 0, lds); SB(0, 0, lds); SA(0, 1, lds); SB(0, 1, lds);
  GUARD4; BAR;

  for (int k = 0; k < 15; ++k) {
    const char* cb = lds + (k & 1) * 65536;
    char* nb = lds + ((k + 1) & 1) * 65536;
    // P1: q0, m0-3
    LDA(cb, 0, 0); LDB(cb, 0);
    SA(k + 1, 0, nb);
    BAR; MM(0); BAR;
    // P2: q0, m4-7  (guard retires this tile's Aq1,Bq1 for P3)
    LDA(cb, 0, 4);
    SB(k + 1, 0, nb);
    GUARD4; BAR; MM(4); BAR;
    // P3: q1, m0-3
    LDA(cb, 1, 0); LDB(cb, 1);
    SA(k + 1, 1, nb);
    BAR; MM(0); BAR;
    // P4: q1, m4-7  (guard retires next tile's Aq0,Bq0 for its P1)
    LDA(cb, 1, 4);
    SB(k + 1, 1, nb);
    GUARD4; BAR; MM(4); BAR;
  }
  {  // Tail tile 15 (buf 1), no staging.
    const char* cb = lds + 65536;
    LDA(cb, 0, 0); LDB(cb, 0);
    BAR; MM(0); BAR;
    LDA(cb, 0, 4);
    GUARD0; BAR; MM(4); BAR;
    LDA(cb, 1, 0); LDB(cb, 1);
    BAR; MM(0); BAR;
    LDA(cb, 1, 4);
    MM(4);
  }
#undef GUARD4
#undef GUARD0
#undef BAR

  // Fused epilogue: gate = acc[m][h], up = acc[m][h+2], h in {0,1}.
  #pragma unroll
  for (int m = 0; m < 8; ++m) {
    const int rbase = wm * 128 + m * 16 + kc * 4;
    #pragma unroll
    for (int i = 0; i < 4; ++i) {
      const int rl = rbase + i;
      if (rl < tile_cnt) {
        const size_t orow = (size_t)s_rows[rl] * OUTN;
        #pragma unroll
        for (int h = 0; h < 2; ++h) {
          float gg = acc[m][h][i];
          float uu = acc[m][h + 2][i];
          float s = gg / (1.0f + __expf(-gg)) * uu;
          Out[orow + c0 + wn * 32 + h * 16 + l15] = s;
        }
      }
    }
  }
}

extern "C" void kernel_launch(void* const* d_in, const int* in_sizes, int n_in,
                              void* d_out, int out_size, void* d_ws, size_t ws_size,
                              hipStream_t stream) {
  const float* H  = (const float*)d_in[0];
  const float* W  = (const float*)d_in[1];
  const int* ids  = (const int*)d_in[2];
  float* Out      = (float*)d_out;
  char* ws        = (char*)d_ws;
  int* wsi        = (int*)ws;
  int* rowlist    = (int*)(ws + WS_ROWLIST);
  unsigned short* Hb = (unsigned short*)(ws + WS_HB);
  unsigned short* Wt = (unsigned short*)(ws + WS_WT);

  hipMemsetAsync(ws, 0, 1024, stream);
  k_detect<<<RFLAT / 2 / 256, 256, 0, stream>>>(ids, wsi);
  k_count<<<RFLAT / 512, 256, 0, stream>>>(ids, wsi);
  k_scan<<<1, 64, 0, stream>>>(wsi);
  k_scatter<<<RFLAT / 256, 256, 0, stream>>>(ids, wsi, rowlist);
  k_cvtH<<<2048, 256, 0, stream>>>(H, Hb);
  k_cvtW<<<dim3(ND / 64, KD / 64, NE), dim3(64, 8), 0, stream>>>(W, Wt);
  // rowtiles (256-row) <= 135; 17 slots per XCD x 8 XCDs x 8 colblocks
  k_gemm<<<8 * 17 * 8, 512, 0, stream>>>(Hb, Wt, wsi, rowlist, Out);
}